// Round 1
// baseline (458.918 us; speedup 1.0000x reference)
//
#include <hip/hip_runtime.h>
#include <hip/hip_bf16.h>

typedef __bf16 bf16x8 __attribute__((ext_vector_type(8)));
typedef float  f32x4  __attribute__((ext_vector_type(4)));
typedef unsigned short u16;
typedef u16    u16x4  __attribute__((ext_vector_type(4)));

static constexpr int LDK = 40; // LDS row stride in bf16 elems: 80B rows, 16B-aligned, 2-way bank alias only

__device__ __forceinline__ u16 f2bf(float f) {
    union { float f; unsigned u; } v; v.f = f;
    unsigned r = v.u + 0x7fffu + ((v.u >> 16) & 1u);
    return (u16)(r >> 16);
}
__device__ __forceinline__ float bf2f(u16 h) {
    union { float f; unsigned u; } v; v.u = ((unsigned)h) << 16; return v.f;
}

// Stage a 128x32 tile of X (row-major, leading dim ld) into LDS as bf16 (+ optional lo residual).
template<typename T, bool SPLIT>
__device__ __forceinline__ void stage_tile(const T* __restrict__ X, int ld, int row0, int k0,
                                           u16* hi, u16* lo) {
    const int t = threadIdx.x;
    const int r = t >> 3;          // 0..31
    const int c = (t & 7) << 2;    // 0,4,...,28
#pragma unroll
    for (int it = 0; it < 4; ++it) {
        const int row = r + (it << 5);
        const T* src = X + (size_t)(row0 + row) * ld + (k0 + c);
        if constexpr (sizeof(T) == 4) {
            f32x4 v = *(const f32x4*)src;
            u16x4 h;
#pragma unroll
            for (int j = 0; j < 4; ++j) h[j] = f2bf(v[j]);
            *(u16x4*)&hi[row * LDK + c] = h;
            if constexpr (SPLIT) {
                u16x4 l4;
#pragma unroll
                for (int j = 0; j < 4; ++j) l4[j] = f2bf(v[j] - bf2f(h[j]));
                *(u16x4*)&lo[row * LDK + c] = l4;
            }
        } else {
            *(u16x4*)&hi[row * LDK + c] = *(const u16x4*)src;
        }
    }
}

// C[M,N] = A[M,K] @ B[N,K]^T + bias, optional split-bf16 (3-pass) precision, optional ReLU.
// TRANSV: write output transposed per-batch into vt[4][512][2048] (B=4, S=2048 hard-coded).
template<typename TA, typename TB, bool SPLIT, bool RELU, typename TC, bool TRANSV>
__global__ __launch_bounds__(256, 2)
void gemm_bt(const TA* __restrict__ A, const TB* __restrict__ B,
             const float* __restrict__ bias, TC* __restrict__ C,
             int M, int N, int K, int lda, int ldb, int ldc,
             long sA, long sB, long sC)
{
    constexpr int BM = 128, BN = 128, BK = 32;
    A += (size_t)blockIdx.z * sA;
    B += (size_t)blockIdx.z * sB;
    C += (size_t)blockIdx.z * sC;
    const int m0 = blockIdx.y * BM, n0 = blockIdx.x * BN;

    __shared__ __align__(16) u16 Ah[BM * LDK];
    __shared__ __align__(16) u16 Bh[BN * LDK];
    __shared__ __align__(16) u16 Al[SPLIT ? BM * LDK : 8];
    __shared__ __align__(16) u16 Bl[SPLIT ? BN * LDK : 8];

    f32x4 acc[4][4] = {};

    const int l  = threadIdx.x & 63;
    const int w  = threadIdx.x >> 6;
    const int wr = (w >> 1) * 64, wc = (w & 1) * 64;
    const int lr = l & 15, kg = l >> 4;

    for (int k0 = 0; k0 < K; k0 += BK) {
        stage_tile<TA, SPLIT>(A, lda, m0, k0, Ah, Al);
        stage_tile<TB, SPLIT>(B, ldb, n0, k0, Bh, Bl);
        __syncthreads();

        bf16x8 af[4], bfr[4];
#pragma unroll
        for (int i = 0; i < 4; ++i) af[i]  = *(const bf16x8*)&Ah[(wr + i * 16 + lr) * LDK + kg * 8];
#pragma unroll
        for (int i = 0; i < 4; ++i) bfr[i] = *(const bf16x8*)&Bh[(wc + i * 16 + lr) * LDK + kg * 8];

        if constexpr (SPLIT) {
            bf16x8 al[4], bl[4];
#pragma unroll
            for (int i = 0; i < 4; ++i) al[i] = *(const bf16x8*)&Al[(wr + i * 16 + lr) * LDK + kg * 8];
#pragma unroll
            for (int i = 0; i < 4; ++i) bl[i] = *(const bf16x8*)&Bl[(wc + i * 16 + lr) * LDK + kg * 8];
#pragma unroll
            for (int mi = 0; mi < 4; ++mi)
#pragma unroll
                for (int ni = 0; ni < 4; ++ni) {
                    acc[mi][ni] = __builtin_amdgcn_mfma_f32_16x16x32_bf16(af[mi], bfr[ni], acc[mi][ni], 0, 0, 0);
                    acc[mi][ni] = __builtin_amdgcn_mfma_f32_16x16x32_bf16(af[mi], bl[ni],  acc[mi][ni], 0, 0, 0);
                    acc[mi][ni] = __builtin_amdgcn_mfma_f32_16x16x32_bf16(al[mi], bfr[ni], acc[mi][ni], 0, 0, 0);
                }
        } else {
#pragma unroll
            for (int mi = 0; mi < 4; ++mi)
#pragma unroll
                for (int ni = 0; ni < 4; ++ni)
                    acc[mi][ni] = __builtin_amdgcn_mfma_f32_16x16x32_bf16(af[mi], bfr[ni], acc[mi][ni], 0, 0, 0);
        }
        __syncthreads();
    }

#pragma unroll
    for (int mi = 0; mi < 4; ++mi) {
        const int mbase = m0 + wr + mi * 16 + kg * 4;
#pragma unroll
        for (int ni = 0; ni < 4; ++ni) {
            const int n = n0 + wc + ni * 16 + lr;
            const float bv = bias ? bias[n] : 0.0f;
            if constexpr (TRANSV) {
                const int bb = mbase >> 11;
                const int s  = mbase & 2047;
                u16x4 o;
#pragma unroll
                for (int j = 0; j < 4; ++j) o[j] = f2bf(acc[mi][ni][j] + bv);
                *(u16x4*)((u16*)C + ((size_t)bb * 512 + n) * 2048 + s) = o;
            } else {
#pragma unroll
                for (int j = 0; j < 4; ++j) {
                    float x = acc[mi][ni][j] + bv;
                    if constexpr (RELU) x = fmaxf(x, 0.0f);
                    const size_t idx = (size_t)(mbase + j) * ldc + n;
                    if constexpr (sizeof(TC) == 4) C[idx] = x;
                    else                           C[idx] = f2bf(x);
                }
            }
        }
    }
}

// Row softmax over [rows][2048] fp32 -> bf16 probabilities.
__global__ __launch_bounds__(256)
void softmax_rows(const float* __restrict__ S, u16* __restrict__ P) {
    const int row = blockIdx.x;
    const float* s = S + (size_t)row * 2048;
    u16* p = P + (size_t)row * 2048;
    const int t = threadIdx.x;
    const int l = t & 63, w = t >> 6;

    f32x4 v0 = *(const f32x4*)&s[t * 8];
    f32x4 v1 = *(const f32x4*)&s[t * 8 + 4];
    float m = v0[0];
#pragma unroll
    for (int j = 1; j < 4; ++j) m = fmaxf(m, v0[j]);
#pragma unroll
    for (int j = 0; j < 4; ++j) m = fmaxf(m, v1[j]);
#pragma unroll
    for (int off = 1; off < 64; off <<= 1) m = fmaxf(m, __shfl_xor(m, off));

    __shared__ float redm[4], reds[4];
    if (l == 0) redm[w] = m;
    __syncthreads();
    m = fmaxf(fmaxf(redm[0], redm[1]), fmaxf(redm[2], redm[3]));

    float e[8]; float sum = 0.0f;
#pragma unroll
    for (int j = 0; j < 4; ++j) { e[j]     = __expf(v0[j] - m); sum += e[j]; }
#pragma unroll
    for (int j = 0; j < 4; ++j) { e[4 + j] = __expf(v1[j] - m); sum += e[4 + j]; }
#pragma unroll
    for (int off = 1; off < 64; off <<= 1) sum += __shfl_xor(sum, off);
    if (l == 0) reds[w] = sum;
    __syncthreads();
    sum = reds[0] + reds[1] + reds[2] + reds[3];
    const float inv = 1.0f / sum;

    u16x4 o0, o1;
#pragma unroll
    for (int j = 0; j < 4; ++j) { o0[j] = f2bf(e[j] * inv); o1[j] = f2bf(e[4 + j] * inv); }
    *(u16x4*)&p[t * 8]     = o0;
    *(u16x4*)&p[t * 8 + 4] = o1;
}

extern "C" void kernel_launch(void* const* d_in, const int* in_sizes, int n_in,
                              void* d_out, int out_size, void* d_ws, size_t ws_size,
                              hipStream_t stream) {
    const float* x  = (const float*)d_in[0];
    const float* Wq = (const float*)d_in[1];
    const float* bq = (const float*)d_in[2];
    const float* Wk = (const float*)d_in[3];
    const float* bk = (const float*)d_in[4];
    const float* Wv = (const float*)d_in[5];
    const float* bv = (const float*)d_in[6];
    const float* W1 = (const float*)d_in[7];
    const float* b1 = (const float*)d_in[8];
    const float* W2 = (const float*)d_in[9];
    const float* b2 = (const float*)d_in[10];
    float* out = (float*)d_out;

    // Workspace layout (with aliasing: attn -> q region, h -> scores region)
    char* ws = (char*)d_ws;
    size_t off = 0;
    auto alloc = [&](size_t bytes) { void* p = ws + off; off += (bytes + 255) & ~(size_t)255; return p; };
    float* q      = (float*)alloc(8192ull * 512 * 4);        // 16.8 MB
    float* kbuf   = (float*)alloc(8192ull * 512 * 4);        // 16.8 MB
    u16*   vt     = (u16*)  alloc(4ull * 512 * 2048 * 2);    //  8.4 MB  [b][d][s]
    float* scores = (float*)alloc(4ull * 2048 * 2048 * 4);   // 67.1 MB
    u16*   P      = (u16*)  alloc(4ull * 2048 * 2048 * 2);   // 33.6 MB
    u16*   attn   = (u16*)q;        // q dead after scores GEMM
    u16*   h      = (u16*)scores;   // scores dead after softmax
    if (ws_size < off) return;      // scratch too small: fail validation loudly

    dim3 blk(256);

    // q = x @ Wq^T + bq   (split precision, fp32 out)
    gemm_bt<float, float, true, false, float, false><<<dim3(4, 64, 1), blk, 0, stream>>>(
        x, Wq, bq, q, 8192, 512, 512, 512, 512, 512, 0, 0, 0);
    // k = x @ Wk^T + bk
    gemm_bt<float, float, true, false, float, false><<<dim3(4, 64, 1), blk, 0, stream>>>(
        x, Wk, bk, kbuf, 8192, 512, 512, 512, 512, 512, 0, 0, 0);
    // vt[b][d][s] = (x @ Wv^T + bv)^T  (bf16, transposed write)
    gemm_bt<float, float, false, false, u16, true><<<dim3(4, 64, 1), blk, 0, stream>>>(
        x, Wv, bv, vt, 8192, 512, 512, 512, 512, 0, 0, 0, 0);
    // scores[b] = q[b] @ k[b]^T   (split precision, fp32 out)
    gemm_bt<float, float, true, false, float, false><<<dim3(16, 16, 4), blk, 0, stream>>>(
        q, kbuf, nullptr, scores, 2048, 2048, 512, 512, 512, 2048,
        2048L * 512, 2048L * 512, 2048L * 2048);
    // P = softmax(scores) rowwise -> bf16
    softmax_rows<<<dim3(8192), blk, 0, stream>>>(scores, P);
    // attn[b] = P[b] @ V[b]  (B operand = vt[b] in [N=512,K=2048] layout)
    gemm_bt<u16, u16, false, false, u16, false><<<dim3(4, 16, 4), blk, 0, stream>>>(
        P, vt, nullptr, attn, 2048, 512, 2048, 2048, 2048, 512,
        2048L * 2048, 512L * 2048, 2048L * 512);
    // h = relu(attn @ W1^T + b1)  (bf16)
    gemm_bt<u16, float, false, true, u16, false><<<dim3(16, 64, 1), blk, 0, stream>>>(
        attn, W1, b1, h, 8192, 2048, 512, 512, 512, 2048, 0, 0, 0);
    // out = h @ W2^T + b2  (fp32)
    gemm_bt<u16, float, false, false, float, false><<<dim3(4, 64, 1), blk, 0, stream>>>(
        h, W2, b2, out, 8192, 512, 2048, 2048, 2048, 512, 0, 0, 0);
}

// Round 2
// 304.906 us; speedup vs baseline: 1.5051x; 1.5051x over previous
//
#include <hip/hip_runtime.h>
#include <hip/hip_bf16.h>

typedef __bf16 bf16x8 __attribute__((ext_vector_type(8)));
typedef float  f32x4  __attribute__((ext_vector_type(4)));
typedef unsigned short u16;
typedef u16    u16x4  __attribute__((ext_vector_type(4)));

__device__ __forceinline__ u16 f2bf(float f) {
    union { float f; unsigned u; } v; v.f = f;
    unsigned r = v.u + 0x7fffu + ((v.u >> 16) & 1u);
    return (u16)(r >> 16);
}
__device__ __forceinline__ float bf2f(u16 h) {
    union { float f; unsigned u; } v; v.u = ((unsigned)h) << 16; return v.f;
}

// fp32 -> bf16 hi (+ optional lo residual), vectorized 4-wide.
template<bool SPLIT>
__global__ __launch_bounds__(256)
void cvt_f32_bf16(const float* __restrict__ X, u16* __restrict__ hi, u16* __restrict__ lo, int n4) {
    const int i = blockIdx.x * 256 + threadIdx.x;
    if (i >= n4) return;
    f32x4 v = ((const f32x4*)X)[i];
    u16x4 h, l4;
#pragma unroll
    for (int j = 0; j < 4; ++j) {
        h[j] = f2bf(v[j]);
        if constexpr (SPLIT) l4[j] = f2bf(v[j] - bf2f(h[j]));
    }
    ((u16x4*)hi)[i] = h;
    if constexpr (SPLIT) ((u16x4*)lo)[i] = l4;
}

// Stage a 128x32 bf16 tile (row-major, leading dim ld elems) into linear LDS [128][32]
// via global_load_lds dwordx4. g0 points at tile origin. lds = tile base (8 KB).
__device__ __forceinline__ void stage128x32(const u16* __restrict__ g0, int ld, u16* lds) {
    const int l = threadIdx.x & 63, w = threadIdx.x >> 6;
#pragma unroll
    for (int i = 0; i < 2; ++i) {
        const int base = ((w << 1) + i) << 10;   // wave-uniform byte offset in tile
        const int off  = base + (l << 4);        // this lane's byte offset
        const int row  = off >> 6;               // 64 B per row (32 bf16)
        const int cb   = off & 63;
        const u16* g = g0 + (size_t)row * ld + (cb >> 1);
        __builtin_amdgcn_global_load_lds((const __attribute__((address_space(1))) void*)g,
                                         (__attribute__((address_space(3))) void*)((char*)lds + base),
                                         16, 0, 0);
    }
}

// C[M,N] = A[M,K] @ B[N,K]^T (+bias). All operands bf16 in HBM, K-contiguous.
// SPLIT: A,B have hi/lo parts -> 3-term MFMA (hh + hl + lh).
// QOUT: write C as bf16 hi into C and residual lo into Clo.
// TRANSV: write output transposed per-batch into [4][512][2048] (B=4,S=2048).
template<bool SPLIT, bool RELU, bool TRANSV, bool QOUT, typename TC>
__global__ __launch_bounds__(256, 2)
void gemm_glds(const u16* __restrict__ Ahg, const u16* __restrict__ Alg,
               const u16* __restrict__ Bhg, const u16* __restrict__ Blg,
               const float* __restrict__ bias, TC* __restrict__ C, u16* __restrict__ Clo,
               int M, int N, int K, int lda, int ldb, int ldc,
               long sA, long sB, long sC)
{
    Ahg += (size_t)blockIdx.z * sA;
    Bhg += (size_t)blockIdx.z * sB;
    C   += (size_t)blockIdx.z * sC;
    const int m0 = blockIdx.y * 128, n0 = blockIdx.x * 128;

    __shared__ __align__(16) u16 smem[(SPLIT ? 4 : 2) * 4096];
    u16* sAh = smem;
    u16* sBh = smem + 4096;
    u16* sAl = smem + (SPLIT ? 8192  : 0);
    u16* sBl = smem + (SPLIT ? 12288 : 0);

    const int l  = threadIdx.x & 63, w = threadIdx.x >> 6;
    const int wr = (w >> 1) * 64, wc = (w & 1) * 64;
    const int lr = l & 15, kg = l >> 4;

    f32x4 acc[4][4] = {};

    const u16* Ab  = Ahg + (size_t)m0 * lda;
    const u16* Bb  = Bhg + (size_t)n0 * ldb;
    const u16* AbL = SPLIT ? (Alg + (size_t)blockIdx.z * sA + (size_t)m0 * lda) : nullptr;
    const u16* BbL = SPLIT ? (Blg + (size_t)blockIdx.z * sB + (size_t)n0 * ldb) : nullptr;

    for (int k0 = 0; k0 < K; k0 += 32) {
        stage128x32(Ab + k0, lda, sAh);
        stage128x32(Bb + k0, ldb, sBh);
        if constexpr (SPLIT) {
            stage128x32(AbL + k0, lda, sAl);
            stage128x32(BbL + k0, ldb, sBl);
        }
        __syncthreads();

        bf16x8 a[4], b[4];
#pragma unroll
        for (int i = 0; i < 4; ++i) a[i] = *(const bf16x8*)&sAh[(wr + i * 16 + lr) * 32 + kg * 8];
#pragma unroll
        for (int i = 0; i < 4; ++i) b[i] = *(const bf16x8*)&sBh[(wc + i * 16 + lr) * 32 + kg * 8];

        if constexpr (SPLIT) {
            bf16x8 al[4], bl[4];
#pragma unroll
            for (int i = 0; i < 4; ++i) al[i] = *(const bf16x8*)&sAl[(wr + i * 16 + lr) * 32 + kg * 8];
#pragma unroll
            for (int i = 0; i < 4; ++i) bl[i] = *(const bf16x8*)&sBl[(wc + i * 16 + lr) * 32 + kg * 8];
#pragma unroll
            for (int mi = 0; mi < 4; ++mi)
#pragma unroll
                for (int ni = 0; ni < 4; ++ni) {
                    acc[mi][ni] = __builtin_amdgcn_mfma_f32_16x16x32_bf16(a[mi],  b[ni],  acc[mi][ni], 0, 0, 0);
                    acc[mi][ni] = __builtin_amdgcn_mfma_f32_16x16x32_bf16(a[mi],  bl[ni], acc[mi][ni], 0, 0, 0);
                    acc[mi][ni] = __builtin_amdgcn_mfma_f32_16x16x32_bf16(al[mi], b[ni],  acc[mi][ni], 0, 0, 0);
                }
        } else {
#pragma unroll
            for (int mi = 0; mi < 4; ++mi)
#pragma unroll
                for (int ni = 0; ni < 4; ++ni)
                    acc[mi][ni] = __builtin_amdgcn_mfma_f32_16x16x32_bf16(a[mi], b[ni], acc[mi][ni], 0, 0, 0);
        }
        __syncthreads();
    }

#pragma unroll
    for (int mi = 0; mi < 4; ++mi) {
        const int mbase = m0 + wr + mi * 16 + kg * 4;
#pragma unroll
        for (int ni = 0; ni < 4; ++ni) {
            const int n = n0 + wc + ni * 16 + lr;
            const float bv = bias ? bias[n] : 0.0f;
            if constexpr (TRANSV) {
                const int bb = mbase >> 11;
                const int s  = mbase & 2047;
                u16x4 o;
#pragma unroll
                for (int j = 0; j < 4; ++j) o[j] = f2bf(acc[mi][ni][j] + bv);
                *(u16x4*)((u16*)C + ((size_t)bb * 512 + n) * 2048 + s) = o;
            } else if constexpr (QOUT) {
#pragma unroll
                for (int j = 0; j < 4; ++j) {
                    const float x = acc[mi][ni][j] + bv;
                    const u16 hbits = f2bf(x);
                    const size_t idx = (size_t)(mbase + j) * ldc + n;
                    ((u16*)C)[idx] = hbits;
                    Clo[idx]       = f2bf(x - bf2f(hbits));
                }
            } else {
#pragma unroll
                for (int j = 0; j < 4; ++j) {
                    float x = acc[mi][ni][j] + bv;
                    if constexpr (RELU) x = fmaxf(x, 0.0f);
                    const size_t idx = (size_t)(mbase + j) * ldc + n;
                    if constexpr (sizeof(TC) == 4) C[idx] = x;
                    else                           C[idx] = f2bf(x);
                }
            }
        }
    }
}

// Row softmax over [rows][2048] fp32 -> bf16 probabilities.
__global__ __launch_bounds__(256)
void softmax_rows(const float* __restrict__ S, u16* __restrict__ P) {
    const int row = blockIdx.x;
    const float* s = S + (size_t)row * 2048;
    u16* p = P + (size_t)row * 2048;
    const int t = threadIdx.x;
    const int l = t & 63, w = t >> 6;

    f32x4 v0 = *(const f32x4*)&s[t * 8];
    f32x4 v1 = *(const f32x4*)&s[t * 8 + 4];
    float m = v0[0];
#pragma unroll
    for (int j = 1; j < 4; ++j) m = fmaxf(m, v0[j]);
#pragma unroll
    for (int j = 0; j < 4; ++j) m = fmaxf(m, v1[j]);
#pragma unroll
    for (int off = 1; off < 64; off <<= 1) m = fmaxf(m, __shfl_xor(m, off));

    __shared__ float redm[4], reds[4];
    if (l == 0) redm[w] = m;
    __syncthreads();
    m = fmaxf(fmaxf(redm[0], redm[1]), fmaxf(redm[2], redm[3]));

    float e[8]; float sum = 0.0f;
#pragma unroll
    for (int j = 0; j < 4; ++j) { e[j]     = __expf(v0[j] - m); sum += e[j]; }
#pragma unroll
    for (int j = 0; j < 4; ++j) { e[4 + j] = __expf(v1[j] - m); sum += e[4 + j]; }
#pragma unroll
    for (int off = 1; off < 64; off <<= 1) sum += __shfl_xor(sum, off);
    if (l == 0) reds[w] = sum;
    __syncthreads();
    sum = reds[0] + reds[1] + reds[2] + reds[3];
    const float inv = 1.0f / sum;

    u16x4 o0, o1;
#pragma unroll
    for (int j = 0; j < 4; ++j) { o0[j] = f2bf(e[j] * inv); o1[j] = f2bf(e[4 + j] * inv); }
    *(u16x4*)&p[t * 8]     = o0;
    *(u16x4*)&p[t * 8 + 4] = o1;
}

extern "C" void kernel_launch(void* const* d_in, const int* in_sizes, int n_in,
                              void* d_out, int out_size, void* d_ws, size_t ws_size,
                              hipStream_t stream) {
    const float* x  = (const float*)d_in[0];
    const float* Wq = (const float*)d_in[1];
    const float* bq = (const float*)d_in[2];
    const float* Wk = (const float*)d_in[3];
    const float* bk = (const float*)d_in[4];
    const float* Wv = (const float*)d_in[5];
    const float* bv = (const float*)d_in[6];
    const float* W1 = (const float*)d_in[7];
    const float* b1 = (const float*)d_in[8];
    const float* W2 = (const float*)d_in[9];
    const float* b2 = (const float*)d_in[10];
    float* out = (float*)d_out;

    char* ws = (char*)d_ws;
    size_t off = 0;
    auto alloc = [&](size_t bytes) { void* p = ws + off; off += (bytes + 255) & ~(size_t)255; return p; };
    u16* x_hi  = (u16*)alloc(8192ull * 512 * 2);      //  8.4 MB
    u16* x_lo  = (u16*)alloc(8192ull * 512 * 2);      //  8.4 MB
    u16* Wq_hi = (u16*)alloc(512ull * 512 * 2);
    u16* Wq_lo = (u16*)alloc(512ull * 512 * 2);
    u16* Wk_hi = (u16*)alloc(512ull * 512 * 2);
    u16* Wk_lo = (u16*)alloc(512ull * 512 * 2);
    u16* Wv_hi = (u16*)alloc(512ull * 512 * 2);
    u16* W1_hi = (u16*)alloc(2048ull * 512 * 2);
    u16* W2_hi = (u16*)alloc(512ull * 2048 * 2);
    u16* q_hi  = (u16*)alloc(8192ull * 512 * 2);      //  8.4 MB  } contiguous 33.6 MB,
    u16* q_lo  = (u16*)alloc(8192ull * 512 * 2);      //  8.4 MB  } re-used as P after
    u16* k_hi  = (u16*)alloc(8192ull * 512 * 2);      //  8.4 MB  } scores GEMM
    u16* k_lo  = (u16*)alloc(8192ull * 512 * 2);      //  8.4 MB  }
    u16* vt    = (u16*)alloc(4ull * 512 * 2048 * 2);  //  8.4 MB  [b][d][s]
    float* scores = (float*)alloc(4ull * 2048 * 2048 * 4); // 67.1 MB
    u16* P    = q_hi;          // 33.6 MB needed == 4*8.4 contiguous; q/k dead after scores
    u16* attn = x_hi;          // 8.4 MB; x dead after v-proj
    u16* h    = (u16*)scores;  // 33.6 MB; scores dead after softmax
    if (ws_size < off) return; // scratch too small: fail validation loudly

    dim3 blk(256);

    // --- one-time operand conversion to bf16 (hi/lo where the scores path needs it) ---
    cvt_f32_bf16<true ><<<dim3(4096), blk, 0, stream>>>(x,  x_hi,  x_lo,  8192 * 512 / 4);
    cvt_f32_bf16<true ><<<dim3(256),  blk, 0, stream>>>(Wq, Wq_hi, Wq_lo, 512 * 512 / 4);
    cvt_f32_bf16<true ><<<dim3(256),  blk, 0, stream>>>(Wk, Wk_hi, Wk_lo, 512 * 512 / 4);
    cvt_f32_bf16<false><<<dim3(256),  blk, 0, stream>>>(Wv, Wv_hi, nullptr, 512 * 512 / 4);
    cvt_f32_bf16<false><<<dim3(1024), blk, 0, stream>>>(W1, W1_hi, nullptr, 2048 * 512 / 4);
    cvt_f32_bf16<false><<<dim3(1024), blk, 0, stream>>>(W2, W2_hi, nullptr, 512 * 2048 / 4);

    // q = x @ Wq^T + bq  (split in, split out)
    gemm_glds<true, false, false, true, u16><<<dim3(4, 64, 1), blk, 0, stream>>>(
        x_hi, x_lo, Wq_hi, Wq_lo, bq, q_hi, q_lo, 8192, 512, 512, 512, 512, 512, 0, 0, 0);
    // k = x @ Wk^T + bk
    gemm_glds<true, false, false, true, u16><<<dim3(4, 64, 1), blk, 0, stream>>>(
        x_hi, x_lo, Wk_hi, Wk_lo, bk, k_hi, k_lo, 8192, 512, 512, 512, 512, 512, 0, 0, 0);
    // vt[b][d][s] = (x @ Wv^T + bv)^T   (bf16)
    gemm_glds<false, false, true, false, u16><<<dim3(4, 64, 1), blk, 0, stream>>>(
        x_hi, nullptr, Wv_hi, nullptr, bv, vt, nullptr, 8192, 512, 512, 512, 512, 0, 0, 0, 0);
    // scores[b] = q[b] @ k[b]^T  (split, fp32 out)
    gemm_glds<true, false, false, false, float><<<dim3(16, 16, 4), blk, 0, stream>>>(
        q_hi, q_lo, k_hi, k_lo, nullptr, scores, nullptr, 2048, 2048, 512, 512, 512, 2048,
        2048L * 512, 2048L * 512, 2048L * 2048);
    // P = softmax(scores) -> bf16
    softmax_rows<<<dim3(8192), blk, 0, stream>>>(scores, P);
    // attn[b] = P[b] @ V[b]   (B operand = vt[b] as [N=512][K=2048])
    gemm_glds<false, false, false, false, u16><<<dim3(4, 16, 4), blk, 0, stream>>>(
        P, nullptr, vt, nullptr, nullptr, attn, nullptr, 2048, 512, 2048, 2048, 2048, 512,
        2048L * 2048, 512L * 2048, 2048L * 512);
    // h = relu(attn @ W1^T + b1)  (bf16)
    gemm_glds<false, true, false, false, u16><<<dim3(16, 64, 1), blk, 0, stream>>>(
        attn, nullptr, W1_hi, nullptr, b1, h, nullptr, 8192, 2048, 512, 512, 512, 2048, 0, 0, 0);
    // out = h @ W2^T + b2  (fp32)
    gemm_glds<false, false, false, false, float><<<dim3(4, 64, 1), blk, 0, stream>>>(
        h, nullptr, W2_hi, nullptr, b2, out, nullptr, 8192, 512, 2048, 2048, 2048, 512, 0, 0, 0);
}

// Round 3
// 249.623 us; speedup vs baseline: 1.8384x; 1.2215x over previous
//
#include <hip/hip_runtime.h>
#include <hip/hip_bf16.h>

typedef __bf16    bf16x8 __attribute__((ext_vector_type(8)));
typedef _Float16  f16x8  __attribute__((ext_vector_type(8)));
typedef float     f32x4  __attribute__((ext_vector_type(4)));
typedef unsigned short u16;
typedef u16       u16x4  __attribute__((ext_vector_type(4)));

__device__ __forceinline__ u16 f2bf(float f) {
    union { float f; unsigned u; } v; v.f = f;
    unsigned r = v.u + 0x7fffu + ((v.u >> 16) & 1u);
    return (u16)(r >> 16);
}
__device__ __forceinline__ float bf2f(u16 h) {
    union { float f; unsigned u; } v; v.u = ((unsigned)h) << 16; return v.f;
}
__device__ __forceinline__ u16 f2h_bits(float f) {
    union { _Float16 h; u16 u; } v; v.h = (_Float16)f; return v.u;
}

// fp32 -> bf16 hi (+ optional lo residual), vectorized 4-wide.
template<bool SPLIT>
__global__ __launch_bounds__(256)
void cvt_f32_bf16(const float* __restrict__ X, u16* __restrict__ hi, u16* __restrict__ lo, int n4) {
    const int i = blockIdx.x * 256 + threadIdx.x;
    if (i >= n4) return;
    f32x4 v = ((const f32x4*)X)[i];
    u16x4 h, l4;
#pragma unroll
    for (int j = 0; j < 4; ++j) {
        h[j] = f2bf(v[j]);
        if constexpr (SPLIT) l4[j] = f2bf(v[j] - bf2f(h[j]));
    }
    ((u16x4*)hi)[i] = h;
    if constexpr (SPLIT) ((u16x4*)lo)[i] = l4;
}

// Stage a 128x32 16-bit tile (row-major, leading dim ld elems) into linear LDS [128][32]
// via global_load_lds dwordx4.
__device__ __forceinline__ void stage128x32(const u16* __restrict__ g0, int ld, u16* lds) {
    const int l = threadIdx.x & 63, w = threadIdx.x >> 6;
#pragma unroll
    for (int i = 0; i < 2; ++i) {
        const int base = ((w << 1) + i) << 10;   // wave-uniform byte offset in tile
        const int off  = base + (l << 4);        // this lane's byte offset
        const int row  = off >> 6;               // 64 B per row (32 elems)
        const int cb   = off & 63;
        const u16* g = g0 + (size_t)row * ld + (cb >> 1);
        __builtin_amdgcn_global_load_lds((const __attribute__((address_space(1))) void*)g,
                                         (__attribute__((address_space(3))) void*)((char*)lds + base),
                                         16, 0, 0);
    }
}

// C[M,N] = A[M,K] @ B[N,K]^T (+bias). 16-bit operands in HBM, K-contiguous.
// SPLIT: A,B have bf16 hi/lo parts -> 3-term MFMA. FP16: operands are fp16, single MFMA.
// OMODE: 0 = fp32 out, 1 = bf16 out, 2 = fp16 out, 3 = transposed-V bf16 out [4][512][2048].
template<bool SPLIT, bool FP16, bool RELU, int OMODE, typename TC>
__global__ __launch_bounds__(256, 2)
void gemm_glds(const u16* __restrict__ Ahg, const u16* __restrict__ Alg,
               const u16* __restrict__ Bhg, const u16* __restrict__ Blg,
               const float* __restrict__ bias, TC* __restrict__ C,
               int K, int lda, int ldb, int ldc,
               long sA, long sB, long sC)
{
    // XCD-aware bijective swizzle (all grids have nwg % 8 == 0).
    const int nx = gridDim.x, ny = gridDim.y;
    const int nwg = nx * ny * gridDim.z;
    int bid = blockIdx.x + nx * (blockIdx.y + ny * blockIdx.z);
    int swz = (bid & 7) * (nwg >> 3) + (bid >> 3);
    const int n0 = (swz % nx) * 128; swz /= nx;
    const int m0 = (swz % ny) * 128;
    const int bz = swz / ny;

    Ahg += (size_t)bz * sA;
    Bhg += (size_t)bz * sB;
    C   += (size_t)bz * sC;

    __shared__ __align__(16) u16 smem[(SPLIT ? 4 : 2) * 4096];
    u16* sAh = smem;
    u16* sBh = smem + 4096;
    u16* sAl = smem + (SPLIT ? 8192  : 0);
    u16* sBl = smem + (SPLIT ? 12288 : 0);

    const int l  = threadIdx.x & 63, w = threadIdx.x >> 6;
    const int wr = (w >> 1) * 64, wc = (w & 1) * 64;
    const int lr = l & 15, kg = l >> 4;

    f32x4 acc[4][4] = {};

    const u16* Ab  = Ahg + (size_t)m0 * lda;
    const u16* Bb  = Bhg + (size_t)n0 * ldb;
    const u16* AbL = SPLIT ? (Alg + (size_t)bz * sA + (size_t)m0 * lda) : nullptr;
    const u16* BbL = SPLIT ? (Blg + (size_t)bz * sB + (size_t)n0 * ldb) : nullptr;

    for (int k0 = 0; k0 < K; k0 += 32) {
        stage128x32(Ab + k0, lda, sAh);
        stage128x32(Bb + k0, ldb, sBh);
        if constexpr (SPLIT) {
            stage128x32(AbL + k0, lda, sAl);
            stage128x32(BbL + k0, ldb, sBl);
        }
        __syncthreads();

        if constexpr (FP16) {
            f16x8 a[4], b[4];
#pragma unroll
            for (int i = 0; i < 4; ++i) a[i] = *(const f16x8*)&sAh[(wr + i * 16 + lr) * 32 + kg * 8];
#pragma unroll
            for (int i = 0; i < 4; ++i) b[i] = *(const f16x8*)&sBh[(wc + i * 16 + lr) * 32 + kg * 8];
#pragma unroll
            for (int mi = 0; mi < 4; ++mi)
#pragma unroll
                for (int ni = 0; ni < 4; ++ni)
                    acc[mi][ni] = __builtin_amdgcn_mfma_f32_16x16x32_f16(a[mi], b[ni], acc[mi][ni], 0, 0, 0);
        } else {
            bf16x8 a[4], b[4];
#pragma unroll
            for (int i = 0; i < 4; ++i) a[i] = *(const bf16x8*)&sAh[(wr + i * 16 + lr) * 32 + kg * 8];
#pragma unroll
            for (int i = 0; i < 4; ++i) b[i] = *(const bf16x8*)&sBh[(wc + i * 16 + lr) * 32 + kg * 8];

            if constexpr (SPLIT) {
                bf16x8 al[4], bl[4];
#pragma unroll
                for (int i = 0; i < 4; ++i) al[i] = *(const bf16x8*)&sAl[(wr + i * 16 + lr) * 32 + kg * 8];
#pragma unroll
                for (int i = 0; i < 4; ++i) bl[i] = *(const bf16x8*)&sBl[(wc + i * 16 + lr) * 32 + kg * 8];
#pragma unroll
                for (int mi = 0; mi < 4; ++mi)
#pragma unroll
                    for (int ni = 0; ni < 4; ++ni) {
                        acc[mi][ni] = __builtin_amdgcn_mfma_f32_16x16x32_bf16(a[mi],  b[ni],  acc[mi][ni], 0, 0, 0);
                        acc[mi][ni] = __builtin_amdgcn_mfma_f32_16x16x32_bf16(a[mi],  bl[ni], acc[mi][ni], 0, 0, 0);
                        acc[mi][ni] = __builtin_amdgcn_mfma_f32_16x16x32_bf16(al[mi], b[ni],  acc[mi][ni], 0, 0, 0);
                    }
            } else {
#pragma unroll
                for (int mi = 0; mi < 4; ++mi)
#pragma unroll
                    for (int ni = 0; ni < 4; ++ni)
                        acc[mi][ni] = __builtin_amdgcn_mfma_f32_16x16x32_bf16(a[mi], b[ni], acc[mi][ni], 0, 0, 0);
            }
        }
        __syncthreads();
    }

#pragma unroll
    for (int mi = 0; mi < 4; ++mi) {
        const int mbase = m0 + wr + mi * 16 + kg * 4;
#pragma unroll
        for (int ni = 0; ni < 4; ++ni) {
            const int n = n0 + wc + ni * 16 + lr;
            const float bv = bias ? bias[n] : 0.0f;
            if constexpr (OMODE == 3) {
                const int bb = mbase >> 11;
                const int s  = mbase & 2047;
                u16x4 o;
#pragma unroll
                for (int j = 0; j < 4; ++j) o[j] = f2bf(acc[mi][ni][j] + bv);
                *(u16x4*)((u16*)C + ((size_t)bb * 512 + n) * 2048 + s) = o;
            } else {
#pragma unroll
                for (int j = 0; j < 4; ++j) {
                    float x = acc[mi][ni][j] + bv;
                    if constexpr (RELU) x = fmaxf(x, 0.0f);
                    const size_t idx = (size_t)(mbase + j) * ldc + n;
                    if constexpr (OMODE == 0)      C[idx] = x;
                    else if constexpr (OMODE == 1) ((u16*)C)[idx] = f2bf(x);
                    else                           ((u16*)C)[idx] = f2h_bits(x);
                }
            }
        }
    }
}

// Row softmax over [rows][2048] fp32 -> bf16 probabilities.
__global__ __launch_bounds__(256)
void softmax_rows(const float* __restrict__ S, u16* __restrict__ P) {
    const int row = blockIdx.x;
    const float* s = S + (size_t)row * 2048;
    u16* p = P + (size_t)row * 2048;
    const int t = threadIdx.x;
    const int l = t & 63, w = t >> 6;

    f32x4 v0 = *(const f32x4*)&s[t * 8];
    f32x4 v1 = *(const f32x4*)&s[t * 8 + 4];
    float m = v0[0];
#pragma unroll
    for (int j = 1; j < 4; ++j) m = fmaxf(m, v0[j]);
#pragma unroll
    for (int j = 0; j < 4; ++j) m = fmaxf(m, v1[j]);
#pragma unroll
    for (int off = 1; off < 64; off <<= 1) m = fmaxf(m, __shfl_xor(m, off));

    __shared__ float redm[4], reds[4];
    if (l == 0) redm[w] = m;
    __syncthreads();
    m = fmaxf(fmaxf(redm[0], redm[1]), fmaxf(redm[2], redm[3]));

    float e[8]; float sum = 0.0f;
#pragma unroll
    for (int j = 0; j < 4; ++j) { e[j]     = __expf(v0[j] - m); sum += e[j]; }
#pragma unroll
    for (int j = 0; j < 4; ++j) { e[4 + j] = __expf(v1[j] - m); sum += e[4 + j]; }
#pragma unroll
    for (int off = 1; off < 64; off <<= 1) sum += __shfl_xor(sum, off);
    if (l == 0) reds[w] = sum;
    __syncthreads();
    sum = reds[0] + reds[1] + reds[2] + reds[3];
    const float inv = 1.0f / sum;

    u16x4 o0, o1;
#pragma unroll
    for (int j = 0; j < 4; ++j) { o0[j] = f2bf(e[j] * inv); o1[j] = f2bf(e[4 + j] * inv); }
    *(u16x4*)&p[t * 8]     = o0;
    *(u16x4*)&p[t * 8 + 4] = o1;
}

extern "C" void kernel_launch(void* const* d_in, const int* in_sizes, int n_in,
                              void* d_out, int out_size, void* d_ws, size_t ws_size,
                              hipStream_t stream) {
    const float* x  = (const float*)d_in[0];
    const float* Wq = (const float*)d_in[1];
    const float* bq = (const float*)d_in[2];
    const float* Wk = (const float*)d_in[3];
    const float* bk = (const float*)d_in[4];
    const float* Wv = (const float*)d_in[5];
    const float* bv = (const float*)d_in[6];
    const float* W1 = (const float*)d_in[7];
    const float* b1 = (const float*)d_in[8];
    const float* W2 = (const float*)d_in[9];
    const float* b2 = (const float*)d_in[10];
    float* out = (float*)d_out;

    char* ws = (char*)d_ws;
    size_t off = 0;
    auto alloc = [&](size_t bytes) { void* p = ws + off; off += (bytes + 255) & ~(size_t)255; return p; };
    u16* x_hi  = (u16*)alloc(8192ull * 512 * 2);       //  8.4 MB
    u16* x_lo  = (u16*)alloc(8192ull * 512 * 2);       //  8.4 MB
    u16* Wq_hi = (u16*)alloc(512ull * 512 * 2);
    u16* Wq_lo = (u16*)alloc(512ull * 512 * 2);
    u16* Wk_hi = (u16*)alloc(512ull * 512 * 2);
    u16* Wk_lo = (u16*)alloc(512ull * 512 * 2);
    u16* Wv_hi = (u16*)alloc(512ull * 512 * 2);
    u16* W1_hi = (u16*)alloc(2048ull * 512 * 2);
    u16* W2_hi = (u16*)alloc(512ull * 2048 * 2);
    u16* pbuf  = (u16*)alloc(4ull * 2048 * 2048 * 2);  // 33.6 MB: q,k live here first, then P
    u16* vt    = (u16*)alloc(4ull * 512 * 2048 * 2);   //  8.4 MB  [b][d][s]
    float* scores = (float*)alloc(4ull * 2048 * 2048 * 4); // 67.1 MB
    u16* q    = pbuf;                   // fp16 [8192][512]
    u16* k    = pbuf + 8192ull * 512;   // fp16 [8192][512]
    u16* P    = pbuf;                   // bf16 [4][2048][2048]; q,k dead after scores GEMM
    u16* attn = x_hi;                   // bf16; x dead after v-proj
    u16* h    = (u16*)scores;           // bf16; scores dead after softmax
    if (ws_size < off) return;          // scratch too small: fail validation loudly

    dim3 blk(256);

    // one-time operand conversion
    cvt_f32_bf16<true ><<<dim3(4096), blk, 0, stream>>>(x,  x_hi,  x_lo,  8192 * 512 / 4);
    cvt_f32_bf16<true ><<<dim3(256),  blk, 0, stream>>>(Wq, Wq_hi, Wq_lo, 512 * 512 / 4);
    cvt_f32_bf16<true ><<<dim3(256),  blk, 0, stream>>>(Wk, Wk_hi, Wk_lo, 512 * 512 / 4);
    cvt_f32_bf16<false><<<dim3(256),  blk, 0, stream>>>(Wv, Wv_hi, nullptr, 512 * 512 / 4);
    cvt_f32_bf16<false><<<dim3(1024), blk, 0, stream>>>(W1, W1_hi, nullptr, 2048 * 512 / 4);
    cvt_f32_bf16<false><<<dim3(1024), blk, 0, stream>>>(W2, W2_hi, nullptr, 512 * 2048 / 4);

    // q = x @ Wq^T + bq   (split-bf16 compute, fp16 store)
    gemm_glds<true, false, false, 2, u16><<<dim3(4, 64, 1), blk, 0, stream>>>(
        x_hi, x_lo, Wq_hi, Wq_lo, bq, q, 512, 512, 512, 512, 0, 0, 0);
    // k = x @ Wk^T + bk
    gemm_glds<true, false, false, 2, u16><<<dim3(4, 64, 1), blk, 0, stream>>>(
        x_hi, x_lo, Wk_hi, Wk_lo, bk, k, 512, 512, 512, 512, 0, 0, 0);
    // vt[b][d][s] = (x @ Wv^T + bv)^T   (bf16)
    gemm_glds<false, false, false, 3, u16><<<dim3(4, 64, 1), blk, 0, stream>>>(
        x_hi, nullptr, Wv_hi, nullptr, bv, vt, 512, 512, 512, 0, 0, 0, 0);
    // scores[b] = q[b] @ k[b]^T   (single fp16 MFMA, fp32 out)
    gemm_glds<false, true, false, 0, float><<<dim3(16, 16, 4), blk, 0, stream>>>(
        q, nullptr, k, nullptr, nullptr, scores, 512, 512, 512, 2048,
        2048L * 512, 2048L * 512, 2048L * 2048);
    // P = softmax(scores) -> bf16 (overwrites dead q/k region)
    softmax_rows<<<dim3(8192), blk, 0, stream>>>(scores, P);
    // attn[b] = P[b] @ V[b]
    gemm_glds<false, false, false, 1, u16><<<dim3(4, 16, 4), blk, 0, stream>>>(
        P, nullptr, vt, nullptr, nullptr, attn, 2048, 2048, 2048, 512,
        2048L * 2048, 512L * 2048, 2048L * 512);
    // h = relu(attn @ W1^T + b1)  (bf16)
    gemm_glds<false, false, true, 1, u16><<<dim3(16, 64, 1), blk, 0, stream>>>(
        attn, nullptr, W1_hi, nullptr, b1, h, 512, 512, 512, 2048, 0, 0, 0);
    // out = h @ W2^T + b2  (fp32)
    gemm_glds<false, false, false, 0, float><<<dim3(4, 64, 1), blk, 0, stream>>>(
        h, nullptr, W2_hi, nullptr, b2, out, 2048, 2048, 2048, 512, 0, 0, 0);
}

// Round 4
// 212.472 us; speedup vs baseline: 2.1599x; 1.1749x over previous
//
#include <hip/hip_runtime.h>
#include <hip/hip_bf16.h>

typedef __bf16    bf16x8 __attribute__((ext_vector_type(8)));
typedef _Float16  f16x8  __attribute__((ext_vector_type(8)));
typedef float     f32x4  __attribute__((ext_vector_type(4)));
typedef unsigned short u16;
typedef u16       u16x4  __attribute__((ext_vector_type(4)));

__device__ __forceinline__ u16 f2bf(float f) {
    union { float f; unsigned u; } v; v.f = f;
    unsigned r = v.u + 0x7fffu + ((v.u >> 16) & 1u);
    return (u16)(r >> 16);
}
__device__ __forceinline__ float bf2f(u16 h) {
    union { float f; unsigned u; } v; v.u = ((unsigned)h) << 16; return v.f;
}
__device__ __forceinline__ u16 f2h_bits(float f) {
    union { _Float16 h; u16 u; } v; v.h = (_Float16)f; return v.u;
}

// fp32 -> bf16 hi (+ optional lo residual), vectorized 4-wide.
template<bool SPLIT>
__global__ __launch_bounds__(256)
void cvt_f32_bf16(const float* __restrict__ X, u16* __restrict__ hi, u16* __restrict__ lo, int n4) {
    const int i = blockIdx.x * 256 + threadIdx.x;
    if (i >= n4) return;
    f32x4 v = ((const f32x4*)X)[i];
    u16x4 h, l4;
#pragma unroll
    for (int j = 0; j < 4; ++j) {
        h[j] = f2bf(v[j]);
        if constexpr (SPLIT) l4[j] = f2bf(v[j] - bf2f(h[j]));
    }
    ((u16x4*)hi)[i] = h;
    if constexpr (SPLIT) ((u16x4*)lo)[i] = l4;
}

// Stage a ROWSx32 16-bit tile (row-major, leading dim ld elems) into linear LDS [ROWS][32]
// via global_load_lds dwordx4. ROWS in {64,128}.
template<int ROWS>
__device__ __forceinline__ void stage_rows(const u16* __restrict__ g0, int ld, u16* lds) {
    const int l = threadIdx.x & 63, w = threadIdx.x >> 6;
    constexpr int CH = ROWS / 64;                // 1 KB chunks per wave
#pragma unroll
    for (int i = 0; i < CH; ++i) {
        const int base = (w * CH + i) << 10;     // wave-uniform byte offset in tile
        const int off  = base + (l << 4);        // this lane's byte offset
        const int row  = off >> 6;               // 64 B per row (32 elems)
        const int cb   = off & 63;
        const u16* g = g0 + (size_t)row * ld + (cb >> 1);
        __builtin_amdgcn_global_load_lds((const __attribute__((address_space(1))) void*)g,
                                         (__attribute__((address_space(3))) void*)((char*)lds + base),
                                         16, 0, 0);
    }
}

// C[M,N] = A[M,K] @ B[N,K]^T (+bias). 16-bit operands in HBM, K-contiguous.
// BM fixed 128; BN in {64,128}. Double-buffered LDS, stage-before-compute (T3 minimum 2-phase).
// SPLIT: A,B have bf16 hi/lo parts -> 3-term MFMA. FP16: operands are fp16, single MFMA.
// OMODE: 0 = fp32 out, 1 = bf16 out, 2 = fp16 out, 3 = transposed-V bf16 out [4][512][2048].
template<int BN, bool SPLIT, bool FP16, bool RELU, int OMODE, typename TC>
__global__ __launch_bounds__(256, 2)
void gemm_glds(const u16* __restrict__ Ahg, const u16* __restrict__ Alg,
               const u16* __restrict__ Bhg, const u16* __restrict__ Blg,
               const float* __restrict__ bias, TC* __restrict__ C,
               int K, int lda, int ldb, int ldc,
               long sA, long sB, long sC)
{
    // XCD-aware bijective swizzle (all grids have nwg % 8 == 0).
    const int nx = gridDim.x, ny = gridDim.y;
    const int nwg = nx * ny * gridDim.z;
    int bid = blockIdx.x + nx * (blockIdx.y + ny * blockIdx.z);
    int swz = (bid & 7) * (nwg >> 3) + (bid >> 3);
    const int n0 = (swz % nx) * BN; swz /= nx;
    const int m0 = (swz % ny) * 128;
    const int bz = swz / ny;

    constexpr int FR = (BN == 128) ? 4 : 2;      // 16-row fragments per wave
    constexpr int ATILE = 128 * 32;
    constexpr int BTILE = BN * 32;
    constexpr int BUFSZ = (ATILE + BTILE) * (SPLIT ? 2 : 1);
    __shared__ __align__(16) u16 smem[2 * BUFSZ];

    const int l  = threadIdx.x & 63, w = threadIdx.x >> 6;
    const int wr = (BN == 128) ? (w >> 1) * 64 : w * 32;
    const int wc = (BN == 128) ? (w & 1) * 64 : 0;
    const int lr = l & 15, kg = l >> 4;

    const u16* Ab  = Ahg + (size_t)bz * sA + (size_t)m0 * lda;
    const u16* Bb  = Bhg + (size_t)bz * sB + (size_t)n0 * ldb;
    const u16* AbL = SPLIT ? (Alg + (size_t)bz * sA + (size_t)m0 * lda) : nullptr;
    const u16* BbL = SPLIT ? (Blg + (size_t)bz * sB + (size_t)n0 * ldb) : nullptr;
    C += (size_t)bz * sC;

    auto stage = [&](int buf, int k0) {
        u16* s = smem + buf * BUFSZ;
        stage_rows<128>(Ab + k0, lda, s);
        stage_rows<BN>(Bb + k0, ldb, s + ATILE);
        if constexpr (SPLIT) {
            stage_rows<128>(AbL + k0, lda, s + ATILE + BTILE);
            stage_rows<BN>(BbL + k0, ldb, s + 2 * ATILE + BTILE);
        }
    };

    f32x4 acc[FR][4] = {};

    stage(0, 0);
    __syncthreads();
    int cur = 0;
    for (int k0 = 0; k0 < K; k0 += 32) {
        if (k0 + 32 < K) stage(cur ^ 1, k0 + 32);   // prefetch next tile (in flight across compute)
        const u16* sAh = smem + cur * BUFSZ;
        const u16* sBh = sAh + ATILE;

        if constexpr (FP16) {
            f16x8 a[FR], b[4];
#pragma unroll
            for (int i = 0; i < FR; ++i) a[i] = *(const f16x8*)&sAh[(wr + i * 16 + lr) * 32 + kg * 8];
#pragma unroll
            for (int i = 0; i < 4; ++i)  b[i] = *(const f16x8*)&sBh[(wc + i * 16 + lr) * 32 + kg * 8];
#pragma unroll
            for (int mi = 0; mi < FR; ++mi)
#pragma unroll
                for (int ni = 0; ni < 4; ++ni)
                    acc[mi][ni] = __builtin_amdgcn_mfma_f32_16x16x32_f16(a[mi], b[ni], acc[mi][ni], 0, 0, 0);
        } else {
            bf16x8 a[FR], b[4];
#pragma unroll
            for (int i = 0; i < FR; ++i) a[i] = *(const bf16x8*)&sAh[(wr + i * 16 + lr) * 32 + kg * 8];
#pragma unroll
            for (int i = 0; i < 4; ++i)  b[i] = *(const bf16x8*)&sBh[(wc + i * 16 + lr) * 32 + kg * 8];

            if constexpr (SPLIT) {
                const u16* sAl = sBh + BTILE;
                const u16* sBl = sAl + ATILE;
                bf16x8 al[FR], bl[4];
#pragma unroll
                for (int i = 0; i < FR; ++i) al[i] = *(const bf16x8*)&sAl[(wr + i * 16 + lr) * 32 + kg * 8];
#pragma unroll
                for (int i = 0; i < 4; ++i)  bl[i] = *(const bf16x8*)&sBl[(wc + i * 16 + lr) * 32 + kg * 8];
#pragma unroll
                for (int mi = 0; mi < FR; ++mi)
#pragma unroll
                    for (int ni = 0; ni < 4; ++ni) {
                        acc[mi][ni] = __builtin_amdgcn_mfma_f32_16x16x32_bf16(a[mi],  b[ni],  acc[mi][ni], 0, 0, 0);
                        acc[mi][ni] = __builtin_amdgcn_mfma_f32_16x16x32_bf16(a[mi],  bl[ni], acc[mi][ni], 0, 0, 0);
                        acc[mi][ni] = __builtin_amdgcn_mfma_f32_16x16x32_bf16(al[mi], b[ni],  acc[mi][ni], 0, 0, 0);
                    }
            } else {
#pragma unroll
                for (int mi = 0; mi < FR; ++mi)
#pragma unroll
                    for (int ni = 0; ni < 4; ++ni)
                        acc[mi][ni] = __builtin_amdgcn_mfma_f32_16x16x32_bf16(a[mi], b[ni], acc[mi][ni], 0, 0, 0);
            }
        }
        __syncthreads();
        cur ^= 1;
    }

#pragma unroll
    for (int mi = 0; mi < FR; ++mi) {
        const int mbase = m0 + wr + mi * 16 + kg * 4;
#pragma unroll
        for (int ni = 0; ni < 4; ++ni) {
            const int n = n0 + wc + ni * 16 + lr;
            const float bv = bias ? bias[n] : 0.0f;
            if constexpr (OMODE == 3) {
                const int bb = mbase >> 11;
                const int s  = mbase & 2047;
                u16x4 o;
#pragma unroll
                for (int j = 0; j < 4; ++j) o[j] = f2bf(acc[mi][ni][j] + bv);
                *(u16x4*)((u16*)C + ((size_t)bb * 512 + n) * 2048 + s) = o;
            } else {
#pragma unroll
                for (int j = 0; j < 4; ++j) {
                    float x = acc[mi][ni][j] + bv;
                    if constexpr (RELU) x = fmaxf(x, 0.0f);
                    const size_t idx = (size_t)(mbase + j) * ldc + n;
                    if constexpr (OMODE == 0)      C[idx] = x;
                    else if constexpr (OMODE == 1) ((u16*)C)[idx] = f2bf(x);
                    else                           ((u16*)C)[idx] = f2h_bits(x);
                }
            }
        }
    }
}

// Row softmax over [rows][2048] fp32 -> bf16 probabilities.
__global__ __launch_bounds__(256)
void softmax_rows(const float* __restrict__ S, u16* __restrict__ P) {
    const int row = blockIdx.x;
    const float* s = S + (size_t)row * 2048;
    u16* p = P + (size_t)row * 2048;
    const int t = threadIdx.x;
    const int l = t & 63, w = t >> 6;

    f32x4 v0 = *(const f32x4*)&s[t * 8];
    f32x4 v1 = *(const f32x4*)&s[t * 8 + 4];
    float m = v0[0];
#pragma unroll
    for (int j = 1; j < 4; ++j) m = fmaxf(m, v0[j]);
#pragma unroll
    for (int j = 0; j < 4; ++j) m = fmaxf(m, v1[j]);
#pragma unroll
    for (int off = 1; off < 64; off <<= 1) m = fmaxf(m, __shfl_xor(m, off));

    __shared__ float redm[4], reds[4];
    if (l == 0) redm[w] = m;
    __syncthreads();
    m = fmaxf(fmaxf(redm[0], redm[1]), fmaxf(redm[2], redm[3]));

    float e[8]; float sum = 0.0f;
#pragma unroll
    for (int j = 0; j < 4; ++j) { e[j]     = __expf(v0[j] - m); sum += e[j]; }
#pragma unroll
    for (int j = 0; j < 4; ++j) { e[4 + j] = __expf(v1[j] - m); sum += e[4 + j]; }
#pragma unroll
    for (int off = 1; off < 64; off <<= 1) sum += __shfl_xor(sum, off);
    if (l == 0) reds[w] = sum;
    __syncthreads();
    sum = reds[0] + reds[1] + reds[2] + reds[3];
    const float inv = 1.0f / sum;

    u16x4 o0, o1;
#pragma unroll
    for (int j = 0; j < 4; ++j) { o0[j] = f2bf(e[j] * inv); o1[j] = f2bf(e[4 + j] * inv); }
    *(u16x4*)&p[t * 8]     = o0;
    *(u16x4*)&p[t * 8 + 4] = o1;
}

extern "C" void kernel_launch(void* const* d_in, const int* in_sizes, int n_in,
                              void* d_out, int out_size, void* d_ws, size_t ws_size,
                              hipStream_t stream) {
    const float* x  = (const float*)d_in[0];
    const float* Wq = (const float*)d_in[1];
    const float* bq = (const float*)d_in[2];
    const float* Wk = (const float*)d_in[3];
    const float* bk = (const float*)d_in[4];
    const float* Wv = (const float*)d_in[5];
    const float* bv = (const float*)d_in[6];
    const float* W1 = (const float*)d_in[7];
    const float* b1 = (const float*)d_in[8];
    const float* W2 = (const float*)d_in[9];
    const float* b2 = (const float*)d_in[10];
    float* out = (float*)d_out;

    char* ws = (char*)d_ws;
    size_t off = 0;
    auto alloc = [&](size_t bytes) { void* p = ws + off; off += (bytes + 255) & ~(size_t)255; return p; };
    u16* x_hi  = (u16*)alloc(8192ull * 512 * 2);       //  8.4 MB
    u16* x_lo  = (u16*)alloc(8192ull * 512 * 2);       //  8.4 MB
    u16* Wq_hi = (u16*)alloc(512ull * 512 * 2);
    u16* Wq_lo = (u16*)alloc(512ull * 512 * 2);
    u16* Wk_hi = (u16*)alloc(512ull * 512 * 2);
    u16* Wk_lo = (u16*)alloc(512ull * 512 * 2);
    u16* Wv_hi = (u16*)alloc(512ull * 512 * 2);
    u16* W1_hi = (u16*)alloc(2048ull * 512 * 2);
    u16* W2_hi = (u16*)alloc(512ull * 2048 * 2);
    u16* pbuf  = (u16*)alloc(4ull * 2048 * 2048 * 2);  // 33.6 MB: q,k live here first, then P
    u16* vt    = (u16*)alloc(4ull * 512 * 2048 * 2);   //  8.4 MB  [b][d][s]
    float* scores = (float*)alloc(4ull * 2048 * 2048 * 4); // 67.1 MB
    u16* q    = pbuf;                   // fp16 [8192][512]
    u16* k    = pbuf + 8192ull * 512;   // fp16 [8192][512]
    u16* P    = pbuf;                   // bf16 [4][2048][2048]; q,k dead after scores GEMM
    u16* attn = x_hi;                   // bf16; x dead after v-proj
    u16* h    = (u16*)scores;           // bf16; scores dead after softmax
    if (ws_size < off) return;          // scratch too small: fail validation loudly

    dim3 blk(256);

    // one-time operand conversion
    cvt_f32_bf16<true ><<<dim3(4096), blk, 0, stream>>>(x,  x_hi,  x_lo,  8192 * 512 / 4);
    cvt_f32_bf16<true ><<<dim3(256),  blk, 0, stream>>>(Wq, Wq_hi, Wq_lo, 512 * 512 / 4);
    cvt_f32_bf16<true ><<<dim3(256),  blk, 0, stream>>>(Wk, Wk_hi, Wk_lo, 512 * 512 / 4);
    cvt_f32_bf16<false><<<dim3(256),  blk, 0, stream>>>(Wv, Wv_hi, nullptr, 512 * 512 / 4);
    cvt_f32_bf16<false><<<dim3(1024), blk, 0, stream>>>(W1, W1_hi, nullptr, 2048 * 512 / 4);
    cvt_f32_bf16<false><<<dim3(1024), blk, 0, stream>>>(W2, W2_hi, nullptr, 512 * 2048 / 4);

    // q = x @ Wq^T + bq   (split-bf16 compute, fp16 store)   512 blocks
    gemm_glds<64, true, false, false, 2, u16><<<dim3(8, 64, 1), blk, 0, stream>>>(
        x_hi, x_lo, Wq_hi, Wq_lo, bq, q, 512, 512, 512, 512, 0, 0, 0);
    // k = x @ Wk^T + bk
    gemm_glds<64, true, false, false, 2, u16><<<dim3(8, 64, 1), blk, 0, stream>>>(
        x_hi, x_lo, Wk_hi, Wk_lo, bk, k, 512, 512, 512, 512, 0, 0, 0);
    // vt[b][d][s] = (x @ Wv^T + bv)^T   (bf16)               512 blocks
    gemm_glds<64, false, false, false, 3, u16><<<dim3(8, 64, 1), blk, 0, stream>>>(
        x_hi, nullptr, Wv_hi, nullptr, bv, vt, 512, 512, 512, 0, 0, 0, 0);
    // scores[b] = q[b] @ k[b]^T   (single fp16 MFMA, fp32 out)  1024 blocks
    gemm_glds<128, false, true, false, 0, float><<<dim3(16, 16, 4), blk, 0, stream>>>(
        q, nullptr, k, nullptr, nullptr, scores, 512, 512, 512, 2048,
        2048L * 512, 2048L * 512, 2048L * 2048);
    // P = softmax(scores) -> bf16 (overwrites dead q/k region)
    softmax_rows<<<dim3(8192), blk, 0, stream>>>(scores, P);
    // attn[b] = P[b] @ V[b]                                   512 blocks
    gemm_glds<64, false, false, false, 1, u16><<<dim3(8, 16, 4), blk, 0, stream>>>(
        P, nullptr, vt, nullptr, nullptr, attn, 2048, 2048, 2048, 512,
        2048L * 2048, 512L * 2048, 2048L * 512);
    // h = relu(attn @ W1^T + b1)  (bf16)                      1024 blocks
    gemm_glds<128, false, false, true, 1, u16><<<dim3(16, 64, 1), blk, 0, stream>>>(
        attn, nullptr, W1_hi, nullptr, b1, h, 512, 512, 512, 2048, 0, 0, 0);
    // out = h @ W2^T + b2  (fp32)                             512 blocks
    gemm_glds<64, false, false, false, 0, float><<<dim3(8, 64, 1), blk, 0, stream>>>(
        h, nullptr, W2_hi, nullptr, b2, out, 2048, 2048, 2048, 512, 0, 0, 0);
}

// Round 5
// 206.863 us; speedup vs baseline: 2.2185x; 1.0271x over previous
//
#include <hip/hip_runtime.h>
#include <hip/hip_bf16.h>

typedef __bf16    bf16x8 __attribute__((ext_vector_type(8)));
typedef _Float16  f16x8  __attribute__((ext_vector_type(8)));
typedef float     f32x4  __attribute__((ext_vector_type(4)));
typedef unsigned short u16;
typedef u16       u16x4  __attribute__((ext_vector_type(4)));

__device__ __forceinline__ u16 f2bf(float f) {
    union { float f; unsigned u; } v; v.f = f;
    unsigned r = v.u + 0x7fffu + ((v.u >> 16) & 1u);
    return (u16)(r >> 16);
}
__device__ __forceinline__ float bf2f(u16 h) {
    union { float f; unsigned u; } v; v.u = ((unsigned)h) << 16; return v.f;
}
__device__ __forceinline__ u16 f2h_bits(float f) {
    union { _Float16 h; u16 u; } v; v.h = (_Float16)f; return v.u;
}

// fp32 -> bf16 hi (+ optional lo residual), vectorized 4-wide.
template<bool SPLIT>
__global__ __launch_bounds__(256)
void cvt_f32_bf16(const float* __restrict__ X, u16* __restrict__ hi, u16* __restrict__ lo, int n4) {
    const int i = blockIdx.x * 256 + threadIdx.x;
    if (i >= n4) return;
    f32x4 v = ((const f32x4*)X)[i];
    u16x4 h, l4;
#pragma unroll
    for (int j = 0; j < 4; ++j) {
        h[j] = f2bf(v[j]);
        if constexpr (SPLIT) l4[j] = f2bf(v[j] - bf2f(h[j]));
    }
    ((u16x4*)hi)[i] = h;
    if constexpr (SPLIT) ((u16x4*)lo)[i] = l4;
}

// Two fp32 srcs -> one concatenated bf16 hi/lo dest (for Wq||Wk).
__global__ __launch_bounds__(256)
void cvt2_split(const float* __restrict__ A, const float* __restrict__ B,
                u16* __restrict__ hi, u16* __restrict__ lo, int n4half) {
    const int i = blockIdx.x * 256 + threadIdx.x;
    if (i >= 2 * n4half) return;
    const bool first = i < n4half;
    const int j = first ? i : i - n4half;
    f32x4 v = first ? ((const f32x4*)A)[j] : ((const f32x4*)B)[j];
    u16x4 h, l4;
#pragma unroll
    for (int k = 0; k < 4; ++k) {
        h[k] = f2bf(v[k]);
        l4[k] = f2bf(v[k] - bf2f(h[k]));
    }
    ((u16x4*)hi)[i] = h;
    ((u16x4*)lo)[i] = l4;
}

__global__ __launch_bounds__(256)
void concat2(const float* __restrict__ a, const float* __restrict__ b, float* __restrict__ o, int n) {
    const int i = blockIdx.x * 256 + threadIdx.x;
    if (i < n) o[i] = a[i];
    else if (i < 2 * n) o[i] = b[i - n];
}

// Stage a ROWSx32 16-bit tile (row-major, ld elems) into linear LDS [ROWS][32] via
// global_load_lds dwordx4. 4 waves (wl in 0..3) cooperate.
template<int ROWS>
__device__ __forceinline__ void stage_rows(const u16* __restrict__ g0, int ld, u16* lds, int wl) {
    const int l = threadIdx.x & 63;
    constexpr int CH = ROWS / 64;                // 1 KB chunks per wave
#pragma unroll
    for (int i = 0; i < CH; ++i) {
        const int base = (wl * CH + i) << 10;    // wave-uniform byte offset in tile
        const int off  = base + (l << 4);        // this lane's byte offset
        const int row  = off >> 6;               // 64 B per row (32 elems)
        const int cb   = off & 63;
        const u16* g = g0 + (size_t)row * ld + (cb >> 1);
        __builtin_amdgcn_global_load_lds((const __attribute__((address_space(1))) void*)g,
                                         (__attribute__((address_space(3))) void*)((char*)lds + base),
                                         16, 0, 0);
    }
}

// C[M,N] = A[M,K] @ B[N,K]^T (+bias). 16-bit operands in HBM, K-contiguous.
// BM=128; BN in {64,128}. Double-buffered LDS, stage-before-compute.
// SPLITK=2: 512 threads; waves 0-3 do K/2 low, 4-7 K/2 high (own dbuf), LDS-reduce at end.
// SPLIT: bf16 hi/lo 3-term MFMA. FP16: fp16 operands, single MFMA.
// OMODE: 0 = fp32 out, 1 = bf16 out, 2 = fp16 out, 3 = transposed-V bf16 out [4][512][2048].
template<int BN, int SPLITK, bool SPLIT, bool FP16, bool RELU, int OMODE, typename TC>
__global__ __launch_bounds__(256 * SPLITK, 2 * SPLITK)
void gemm_glds(const u16* __restrict__ Ahg, const u16* __restrict__ Alg,
               const u16* __restrict__ Bhg, const u16* __restrict__ Blg,
               const float* __restrict__ bias, TC* __restrict__ C,
               int K, int lda, int ldb, int ldc,
               long sA, long sB, long sC)
{
    // XCD-aware bijective swizzle (all grids have nwg % 8 == 0).
    const int nx = gridDim.x, ny = gridDim.y;
    const int nwg = nx * ny * gridDim.z;
    int bid = blockIdx.x + nx * (blockIdx.y + ny * blockIdx.z);
    int swz = (bid & 7) * (nwg >> 3) + (bid >> 3);
    const int n0 = (swz % nx) * BN; swz /= nx;
    const int m0 = (swz % ny) * 128;
    const int bz = swz / ny;

    constexpr int FR = (BN == 128) ? 4 : 2;      // 16-row A-fragments per wave
    constexpr int ATILE = 128 * 32;
    constexpr int BTILE = BN * 32;
    constexpr int BUFSZ = (ATILE + BTILE) * (SPLIT ? 2 : 1);
    __shared__ __align__(16) u16 smem[SPLITK * 2 * BUFSZ];

    const int l  = threadIdx.x & 63, w = threadIdx.x >> 6;
    const int kw = (SPLITK == 2) ? (w >> 2) : 0; // k-half id
    const int wl = w & 3;                        // wave id within half
    const int wr = (BN == 128) ? (wl >> 1) * 64 : wl * 32;
    const int wc = (BN == 128) ? (wl & 1) * 64 : 0;
    const int lr = l & 15, kg = l >> 4;

    const int Kh = K / SPLITK;
    const int kb = kw * Kh;

    const u16* Ab  = Ahg + (size_t)bz * sA + (size_t)m0 * lda + kb;
    const u16* Bb  = Bhg + (size_t)bz * sB + (size_t)n0 * ldb + kb;
    const u16* AbL = SPLIT ? (Alg + (size_t)bz * sA + (size_t)m0 * lda + kb) : nullptr;
    const u16* BbL = SPLIT ? (Blg + (size_t)bz * sB + (size_t)n0 * ldb + kb) : nullptr;
    C += (size_t)bz * sC;

    u16* mybuf = smem + kw * 2 * BUFSZ;

    auto stage = [&](int buf, int k0) {
        u16* s = mybuf + buf * BUFSZ;
        stage_rows<128>(Ab + k0, lda, s, wl);
        stage_rows<BN>(Bb + k0, ldb, s + ATILE, wl);
        if constexpr (SPLIT) {
            stage_rows<128>(AbL + k0, lda, s + ATILE + BTILE, wl);
            stage_rows<BN>(BbL + k0, ldb, s + 2 * ATILE + BTILE, wl);
        }
    };

    f32x4 acc[FR][4] = {};

    stage(0, 0);
    __syncthreads();
    int cur = 0;
    for (int k0 = 0; k0 < Kh; k0 += 32) {
        if (k0 + 32 < Kh) stage(cur ^ 1, k0 + 32);   // prefetch next tile
        const u16* sAh = mybuf + cur * BUFSZ;
        const u16* sBh = sAh + ATILE;

        if constexpr (FP16) {
            f16x8 a[FR], b[4];
#pragma unroll
            for (int i = 0; i < FR; ++i) a[i] = *(const f16x8*)&sAh[(wr + i * 16 + lr) * 32 + kg * 8];
#pragma unroll
            for (int i = 0; i < 4; ++i)  b[i] = *(const f16x8*)&sBh[(wc + i * 16 + lr) * 32 + kg * 8];
#pragma unroll
            for (int mi = 0; mi < FR; ++mi)
#pragma unroll
                for (int ni = 0; ni < 4; ++ni)
                    acc[mi][ni] = __builtin_amdgcn_mfma_f32_16x16x32_f16(a[mi], b[ni], acc[mi][ni], 0, 0, 0);
        } else {
            bf16x8 a[FR], b[4];
#pragma unroll
            for (int i = 0; i < FR; ++i) a[i] = *(const bf16x8*)&sAh[(wr + i * 16 + lr) * 32 + kg * 8];
#pragma unroll
            for (int i = 0; i < 4; ++i)  b[i] = *(const bf16x8*)&sBh[(wc + i * 16 + lr) * 32 + kg * 8];

            if constexpr (SPLIT) {
                const u16* sAl = sBh + BTILE;
                const u16* sBl = sAl + ATILE;
                bf16x8 al[FR], bl[4];
#pragma unroll
                for (int i = 0; i < FR; ++i) al[i] = *(const bf16x8*)&sAl[(wr + i * 16 + lr) * 32 + kg * 8];
#pragma unroll
                for (int i = 0; i < 4; ++i)  bl[i] = *(const bf16x8*)&sBl[(wc + i * 16 + lr) * 32 + kg * 8];
#pragma unroll
                for (int mi = 0; mi < FR; ++mi)
#pragma unroll
                    for (int ni = 0; ni < 4; ++ni) {
                        acc[mi][ni] = __builtin_amdgcn_mfma_f32_16x16x32_bf16(a[mi],  b[ni],  acc[mi][ni], 0, 0, 0);
                        acc[mi][ni] = __builtin_amdgcn_mfma_f32_16x16x32_bf16(a[mi],  bl[ni], acc[mi][ni], 0, 0, 0);
                        acc[mi][ni] = __builtin_amdgcn_mfma_f32_16x16x32_bf16(al[mi], b[ni],  acc[mi][ni], 0, 0, 0);
                    }
            } else {
#pragma unroll
                for (int mi = 0; mi < FR; ++mi)
#pragma unroll
                    for (int ni = 0; ni < 4; ++ni)
                        acc[mi][ni] = __builtin_amdgcn_mfma_f32_16x16x32_bf16(a[mi], b[ni], acc[mi][ni], 0, 0, 0);
            }
        }
        __syncthreads();
        cur ^= 1;
    }

    if constexpr (SPLITK == 2) {
        // reduce high-half partials into low-half acc via LDS (reuse staging LDS)
        float* red = (float*)smem;
        const int slot = (wl * 64 + l) * (FR * 4);
        if (kw == 1) {
#pragma unroll
            for (int mi = 0; mi < FR; ++mi)
#pragma unroll
                for (int ni = 0; ni < 4; ++ni)
                    *(f32x4*)&red[(slot + mi * 4 + ni) * 4] = acc[mi][ni];
        }
        __syncthreads();
        if (kw == 1) return;
#pragma unroll
        for (int mi = 0; mi < FR; ++mi)
#pragma unroll
            for (int ni = 0; ni < 4; ++ni)
                acc[mi][ni] += *(const f32x4*)&red[(slot + mi * 4 + ni) * 4];
    }

#pragma unroll
    for (int mi = 0; mi < FR; ++mi) {
        const int mbase = m0 + wr + mi * 16 + kg * 4;
#pragma unroll
        for (int ni = 0; ni < 4; ++ni) {
            const int n = n0 + wc + ni * 16 + lr;
            const float bv = bias ? bias[n] : 0.0f;
            if constexpr (OMODE == 3) {
                const int bb = mbase >> 11;
                const int s  = mbase & 2047;
                u16x4 o;
#pragma unroll
                for (int j = 0; j < 4; ++j) o[j] = f2bf(acc[mi][ni][j] + bv);
                *(u16x4*)((u16*)C + ((size_t)bb * 512 + n) * 2048 + s) = o;
            } else {
#pragma unroll
                for (int j = 0; j < 4; ++j) {
                    float x = acc[mi][ni][j] + bv;
                    if constexpr (RELU) x = fmaxf(x, 0.0f);
                    const size_t idx = (size_t)(mbase + j) * ldc + n;
                    if constexpr (OMODE == 0)      C[idx] = x;
                    else if constexpr (OMODE == 1) ((u16*)C)[idx] = f2bf(x);
                    else                           ((u16*)C)[idx] = f2h_bits(x);
                }
            }
        }
    }
}

// Row softmax over [rows][2048] fp32 -> bf16 probabilities.
__global__ __launch_bounds__(256)
void softmax_rows(const float* __restrict__ S, u16* __restrict__ P) {
    const int row = blockIdx.x;
    const float* s = S + (size_t)row * 2048;
    u16* p = P + (size_t)row * 2048;
    const int t = threadIdx.x;
    const int l = t & 63, w = t >> 6;

    f32x4 v0 = *(const f32x4*)&s[t * 8];
    f32x4 v1 = *(const f32x4*)&s[t * 8 + 4];
    float m = v0[0];
#pragma unroll
    for (int j = 1; j < 4; ++j) m = fmaxf(m, v0[j]);
#pragma unroll
    for (int j = 0; j < 4; ++j) m = fmaxf(m, v1[j]);
#pragma unroll
    for (int off = 1; off < 64; off <<= 1) m = fmaxf(m, __shfl_xor(m, off));

    __shared__ float redm[4], reds[4];
    if (l == 0) redm[w] = m;
    __syncthreads();
    m = fmaxf(fmaxf(redm[0], redm[1]), fmaxf(redm[2], redm[3]));

    float e[8]; float sum = 0.0f;
#pragma unroll
    for (int j = 0; j < 4; ++j) { e[j]     = __expf(v0[j] - m); sum += e[j]; }
#pragma unroll
    for (int j = 0; j < 4; ++j) { e[4 + j] = __expf(v1[j] - m); sum += e[4 + j]; }
#pragma unroll
    for (int off = 1; off < 64; off <<= 1) sum += __shfl_xor(sum, off);
    if (l == 0) reds[w] = sum;
    __syncthreads();
    sum = reds[0] + reds[1] + reds[2] + reds[3];
    const float inv = 1.0f / sum;

    u16x4 o0, o1;
#pragma unroll
    for (int j = 0; j < 4; ++j) { o0[j] = f2bf(e[j] * inv); o1[j] = f2bf(e[4 + j] * inv); }
    *(u16x4*)&p[t * 8]     = o0;
    *(u16x4*)&p[t * 8 + 4] = o1;
}

extern "C" void kernel_launch(void* const* d_in, const int* in_sizes, int n_in,
                              void* d_out, int out_size, void* d_ws, size_t ws_size,
                              hipStream_t stream) {
    const float* x  = (const float*)d_in[0];
    const float* Wq = (const float*)d_in[1];
    const float* bq = (const float*)d_in[2];
    const float* Wk = (const float*)d_in[3];
    const float* bk = (const float*)d_in[4];
    const float* Wv = (const float*)d_in[5];
    const float* bv = (const float*)d_in[6];
    const float* W1 = (const float*)d_in[7];
    const float* b1 = (const float*)d_in[8];
    const float* W2 = (const float*)d_in[9];
    const float* b2 = (const float*)d_in[10];
    float* out = (float*)d_out;

    char* ws = (char*)d_ws;
    size_t off = 0;
    auto alloc = [&](size_t bytes) { void* p = ws + off; off += (bytes + 255) & ~(size_t)255; return p; };
    u16* x_hi   = (u16*)alloc(8192ull * 512 * 2);       //  8.4 MB
    u16* x_lo   = (u16*)alloc(8192ull * 512 * 2);       //  8.4 MB
    u16* Wqk_hi = (u16*)alloc(1024ull * 512 * 2);       //  Wq rows 0-511, Wk rows 512-1023
    u16* Wqk_lo = (u16*)alloc(1024ull * 512 * 2);
    u16* Wv_hi  = (u16*)alloc(512ull * 512 * 2);
    u16* W1_hi  = (u16*)alloc(2048ull * 512 * 2);
    u16* W2_hi  = (u16*)alloc(512ull * 2048 * 2);
    float* bqk  = (float*)alloc(1024 * 4);
    u16* pbuf   = (u16*)alloc(4ull * 2048 * 2048 * 2);  // 33.6 MB: qk lives here first, then P
    u16* vt     = (u16*)alloc(4ull * 512 * 2048 * 2);   //  8.4 MB  [b][d][s]
    float* scores = (float*)alloc(4ull * 2048 * 2048 * 4); // 67.1 MB
    u16* qk   = pbuf;                   // fp16 [8192][1024]: q cols 0-511, k cols 512-1023
    u16* P    = pbuf;                   // bf16 [4][2048][2048]; qk dead after scores GEMM
    u16* attn = x_hi;                   // bf16; x dead after v-proj
    u16* h    = (u16*)scores;           // bf16; scores dead after softmax
    if (ws_size < off) return;          // scratch too small: fail validation loudly

    dim3 blk(256), blk2(512);

    // one-time operand conversion
    cvt_f32_bf16<true ><<<dim3(4096), blk, 0, stream>>>(x,  x_hi,  x_lo,  8192 * 512 / 4);
    cvt2_split<<<dim3(512), blk, 0, stream>>>(Wq, Wk, Wqk_hi, Wqk_lo, 512 * 512 / 4);
    cvt_f32_bf16<false><<<dim3(256),  blk, 0, stream>>>(Wv, Wv_hi, nullptr, 512 * 512 / 4);
    cvt_f32_bf16<false><<<dim3(1024), blk, 0, stream>>>(W1, W1_hi, nullptr, 2048 * 512 / 4);
    cvt_f32_bf16<false><<<dim3(1024), blk, 0, stream>>>(W2, W2_hi, nullptr, 512 * 2048 / 4);
    concat2<<<dim3(4), blk, 0, stream>>>(bq, bk, bqk, 512);

    // qk = x @ [Wq;Wk]^T + [bq;bk]   (split-bf16 compute, fp16 store)   512 blocks
    gemm_glds<128, 1, true, false, false, 2, u16><<<dim3(8, 64, 1), blk, 0, stream>>>(
        x_hi, x_lo, Wqk_hi, Wqk_lo, bqk, qk, 512, 512, 512, 1024, 0, 0, 0);
    // vt[b][d][s] = (x @ Wv^T + bv)^T   (bf16)   512 blocks, splitK=2
    gemm_glds<64, 2, false, false, false, 3, u16><<<dim3(8, 64, 1), blk2, 0, stream>>>(
        x_hi, nullptr, Wv_hi, nullptr, bv, vt, 512, 512, 512, 0, 0, 0, 0);
    // scores[b] = q[b] @ k[b]^T   (single fp16 MFMA, fp32 out)   1024 blocks
    gemm_glds<128, 1, false, true, false, 0, float><<<dim3(16, 16, 4), blk, 0, stream>>>(
        qk, nullptr, qk + 512, nullptr, nullptr, scores, 512, 1024, 1024, 2048,
        2048L * 1024, 2048L * 1024, 2048L * 2048);
    // P = softmax(scores) -> bf16 (overwrites dead qk region)
    softmax_rows<<<dim3(8192), blk, 0, stream>>>(scores, P);
    // attn[b] = P[b] @ V[b]   512 blocks, splitK=2
    gemm_glds<64, 2, false, false, false, 1, u16><<<dim3(8, 16, 4), blk2, 0, stream>>>(
        P, nullptr, vt, nullptr, nullptr, attn, 2048, 2048, 2048, 512,
        2048L * 2048, 512L * 2048, 2048L * 512);
    // h = relu(attn @ W1^T + b1)  (bf16)   1024 blocks
    gemm_glds<128, 1, false, false, true, 1, u16><<<dim3(16, 64, 1), blk, 0, stream>>>(
        attn, nullptr, W1_hi, nullptr, b1, h, 512, 512, 512, 2048, 0, 0, 0);
    // out = h @ W2^T + b2  (fp32)   512 blocks, splitK=2
    gemm_glds<64, 2, false, false, false, 0, float><<<dim3(8, 64, 1), blk2, 0, stream>>>(
        h, nullptr, W2_hi, nullptr, b2, out, 2048, 2048, 2048, 512, 0, 0, 0);
}

// Round 6
// 192.144 us; speedup vs baseline: 2.3884x; 1.0766x over previous
//
#include <hip/hip_runtime.h>
#include <hip/hip_bf16.h>

typedef _Float16  f16x8  __attribute__((ext_vector_type(8)));
typedef float     f32x4  __attribute__((ext_vector_type(4)));
typedef unsigned short u16;
typedef u16       u16x4  __attribute__((ext_vector_type(4)));

__device__ __forceinline__ u16 f2h_bits(float f) {
    union { _Float16 h; u16 u; } v; v.h = (_Float16)f; return v.u;
}

// fp32 -> fp16, vectorized 4-wide.
__global__ __launch_bounds__(256)
void cvt_f32_f16(const float* __restrict__ X, u16* __restrict__ o, int n4) {
    const int i = blockIdx.x * 256 + threadIdx.x;
    if (i >= n4) return;
    f32x4 v = ((const f32x4*)X)[i];
    u16x4 h;
#pragma unroll
    for (int j = 0; j < 4; ++j) h[j] = f2h_bits(v[j]);
    ((u16x4*)o)[i] = h;
}

// All weight conversions + bias concat in ONE dispatch.
// Segments (vec4 units): Wq 65536 -> Wqk[0:], Wk 65536 -> Wqk[65536:], Wv 65536,
// W1 262144, W2 262144, then 256 vec4 of biases (bq||bk -> bqk fp32).
__global__ __launch_bounds__(256)
void cvt_weights(const float* __restrict__ Wq, const float* __restrict__ Wk,
                 const float* __restrict__ Wv, const float* __restrict__ W1,
                 const float* __restrict__ W2, const float* __restrict__ bq,
                 const float* __restrict__ bk,
                 u16* __restrict__ Wqk16, u16* __restrict__ Wv16,
                 u16* __restrict__ W116, u16* __restrict__ W216, float* __restrict__ bqk) {
    const int i = blockIdx.x * 256 + threadIdx.x;
    constexpr int S = 512 * 512 / 4, L = 2048 * 512 / 4;
    const float* src; u16* dst; int j;
    if      (i <     S)         { src = Wq; dst = Wqk16;           j = i;             }
    else if (i < 2 * S)         { src = Wk; dst = Wqk16 + 4 * S;   j = i - S;         }
    else if (i < 3 * S)         { src = Wv; dst = Wv16;            j = i - 2 * S;     }
    else if (i < 3 * S + L)     { src = W1; dst = W116;            j = i - 3 * S;     }
    else if (i < 3 * S + 2 * L) { src = W2; dst = W216;            j = i - 3 * S - L; }
    else if (i < 3 * S + 2 * L + 256) {
        const int g = (i - 3 * S - 2 * L) * 4;
#pragma unroll
        for (int t = 0; t < 4; ++t) bqk[g + t] = (g + t < 512) ? bq[g + t] : bk[g + t - 512];
        return;
    } else return;
    f32x4 v = ((const f32x4*)src)[j];
    u16x4 h;
#pragma unroll
    for (int t = 0; t < 4; ++t) h[t] = f2h_bits(v[t]);
    ((u16x4*)dst)[j] = h;
}

// Stage a ROWSx32 16-bit tile (row-major, ld elems) into linear LDS [ROWS][32] via
// global_load_lds dwordx4. 4 waves (wl in 0..3) cooperate.
template<int ROWS>
__device__ __forceinline__ void stage_rows(const u16* __restrict__ g0, int ld, u16* lds, int wl) {
    const int l = threadIdx.x & 63;
    constexpr int CH = ROWS / 64;                // 1 KB chunks per wave
#pragma unroll
    for (int i = 0; i < CH; ++i) {
        const int base = (wl * CH + i) << 10;    // wave-uniform byte offset in tile
        const int off  = base + (l << 4);
        const int row  = off >> 6;               // 64 B per row (32 elems)
        const int cb   = off & 63;
        const u16* g = g0 + (size_t)row * ld + (cb >> 1);
        __builtin_amdgcn_global_load_lds((const __attribute__((address_space(1))) void*)g,
                                         (__attribute__((address_space(3))) void*)((char*)lds + base),
                                         16, 0, 0);
    }
}

// C[M,N] = A[M,K] @ B[N,K]^T (+bias). fp16 operands, fp32 accumulate.
// BM=128; BN in {64,128}. Double-buffered LDS, stage-before-compute.
// SPLITK=2: 512 threads; waves 0-3 do K/2 low, 4-7 high (own dbuf), LDS-reduce.
// OMODE: 0 = fp32 out, 2 = fp16 out, 3 = transposed-V fp16 out [4][512][2048].
template<int BN, int SPLITK, bool RELU, int OMODE, typename TC>
__global__ __launch_bounds__(256 * SPLITK, 4)
void gemm16(const u16* __restrict__ Ag, const u16* __restrict__ Bg,
            const float* __restrict__ bias, TC* __restrict__ C,
            int K, int lda, int ldb, int ldc,
            long sA, long sB, long sC)
{
    // XCD-aware bijective swizzle (all grids have nwg % 8 == 0).
    const int nx = gridDim.x, ny = gridDim.y;
    const int nwg = nx * ny * gridDim.z;
    int bid = blockIdx.x + nx * (blockIdx.y + ny * blockIdx.z);
    int swz = (bid & 7) * (nwg >> 3) + (bid >> 3);
    const int n0 = (swz % nx) * BN; swz /= nx;
    const int m0 = (swz % ny) * 128;
    const int bz = swz / ny;

    constexpr int FR = (BN == 128) ? 4 : 2;      // 16-row A-fragments per wave
    constexpr int ATILE = 128 * 32;
    constexpr int BTILE = BN * 32;
    constexpr int BUFSZ = ATILE + BTILE;
    __shared__ __align__(16) u16 smem[SPLITK * 2 * BUFSZ];

    const int l  = threadIdx.x & 63, w = threadIdx.x >> 6;
    const int kw = (SPLITK == 2) ? (w >> 2) : 0; // k-half id
    const int wl = w & 3;                        // wave id within half
    const int wr = (BN == 128) ? (wl >> 1) * 64 : wl * 32;
    const int wc = (BN == 128) ? (wl & 1) * 64 : 0;
    const int lr = l & 15, kg = l >> 4;

    const int Kh = K / SPLITK;
    const int kb = kw * Kh;

    const u16* Ab = Ag + (size_t)bz * sA + (size_t)m0 * lda + kb;
    const u16* Bb = Bg + (size_t)bz * sB + (size_t)n0 * ldb + kb;
    C += (size_t)bz * sC;

    u16* mybuf = smem + kw * 2 * BUFSZ;

    auto stage = [&](int buf, int k0) {
        u16* s = mybuf + buf * BUFSZ;
        stage_rows<128>(Ab + k0, lda, s, wl);
        stage_rows<BN>(Bb + k0, ldb, s + ATILE, wl);
    };

    f32x4 acc[FR][4] = {};

    stage(0, 0);
    __syncthreads();
    int cur = 0;
    for (int k0 = 0; k0 < Kh; k0 += 32) {
        if (k0 + 32 < Kh) stage(cur ^ 1, k0 + 32);   // prefetch next tile
        const u16* sA = mybuf + cur * BUFSZ;
        const u16* sB = sA + ATILE;

        f16x8 a[FR], b[4];
#pragma unroll
        for (int i = 0; i < FR; ++i) a[i] = *(const f16x8*)&sA[(wr + i * 16 + lr) * 32 + kg * 8];
#pragma unroll
        for (int i = 0; i < 4; ++i)  b[i] = *(const f16x8*)&sB[(wc + i * 16 + lr) * 32 + kg * 8];
#pragma unroll
        for (int mi = 0; mi < FR; ++mi)
#pragma unroll
            for (int ni = 0; ni < 4; ++ni)
                acc[mi][ni] = __builtin_amdgcn_mfma_f32_16x16x32_f16(a[mi], b[ni], acc[mi][ni], 0, 0, 0);
        __syncthreads();
        cur ^= 1;
    }

    if constexpr (SPLITK == 2) {
        // reduce high-half partials into low-half acc via LDS (reuse staging LDS)
        float* red = (float*)smem;
        const int slot = (wl * 64 + l) * (FR * 4);
        if (kw == 1) {
#pragma unroll
            for (int mi = 0; mi < FR; ++mi)
#pragma unroll
                for (int ni = 0; ni < 4; ++ni)
                    *(f32x4*)&red[(slot + mi * 4 + ni) * 4] = acc[mi][ni];
        }
        __syncthreads();
        if (kw == 1) return;
#pragma unroll
        for (int mi = 0; mi < FR; ++mi)
#pragma unroll
            for (int ni = 0; ni < 4; ++ni)
                acc[mi][ni] += *(const f32x4*)&red[(slot + mi * 4 + ni) * 4];
    }

#pragma unroll
    for (int mi = 0; mi < FR; ++mi) {
        const int mbase = m0 + wr + mi * 16 + kg * 4;
#pragma unroll
        for (int ni = 0; ni < 4; ++ni) {
            const int n = n0 + wc + ni * 16 + lr;
            const float bv = bias ? bias[n] : 0.0f;
            if constexpr (OMODE == 3) {
                const int bb = mbase >> 11;
                const int s  = mbase & 2047;
                u16x4 o;
#pragma unroll
                for (int j = 0; j < 4; ++j) o[j] = f2h_bits(acc[mi][ni][j] + bv);
                *(u16x4*)((u16*)C + ((size_t)bb * 512 + n) * 2048 + s) = o;
            } else {
#pragma unroll
                for (int j = 0; j < 4; ++j) {
                    float x = acc[mi][ni][j] + bv;
                    if constexpr (RELU) x = fmaxf(x, 0.0f);
                    const size_t idx = (size_t)(mbase + j) * ldc + n;
                    if constexpr (OMODE == 0) C[idx] = x;
                    else                      ((u16*)C)[idx] = f2h_bits(x);
                }
            }
        }
    }
}

// Row softmax over [rows][2048] fp32 -> fp16 probabilities.
__global__ __launch_bounds__(256)
void softmax_rows(const float* __restrict__ S, u16* __restrict__ P) {
    const int row = blockIdx.x;
    const float* s = S + (size_t)row * 2048;
    u16* p = P + (size_t)row * 2048;
    const int t = threadIdx.x;
    const int l = t & 63, w = t >> 6;

    f32x4 v0 = *(const f32x4*)&s[t * 8];
    f32x4 v1 = *(const f32x4*)&s[t * 8 + 4];
    float m = v0[0];
#pragma unroll
    for (int j = 1; j < 4; ++j) m = fmaxf(m, v0[j]);
#pragma unroll
    for (int j = 0; j < 4; ++j) m = fmaxf(m, v1[j]);
#pragma unroll
    for (int off = 1; off < 64; off <<= 1) m = fmaxf(m, __shfl_xor(m, off));

    __shared__ float redm[4], reds[4];
    if (l == 0) redm[w] = m;
    __syncthreads();
    m = fmaxf(fmaxf(redm[0], redm[1]), fmaxf(redm[2], redm[3]));

    float e[8]; float sum = 0.0f;
#pragma unroll
    for (int j = 0; j < 4; ++j) { e[j]     = __expf(v0[j] - m); sum += e[j]; }
#pragma unroll
    for (int j = 0; j < 4; ++j) { e[4 + j] = __expf(v1[j] - m); sum += e[4 + j]; }
#pragma unroll
    for (int off = 1; off < 64; off <<= 1) sum += __shfl_xor(sum, off);
    if (l == 0) reds[w] = sum;
    __syncthreads();
    sum = reds[0] + reds[1] + reds[2] + reds[3];
    const float inv = 1.0f / sum;

    u16x4 o0, o1;
#pragma unroll
    for (int j = 0; j < 4; ++j) { o0[j] = f2h_bits(e[j] * inv); o1[j] = f2h_bits(e[4 + j] * inv); }
    *(u16x4*)&p[t * 8]     = o0;
    *(u16x4*)&p[t * 8 + 4] = o1;
}

extern "C" void kernel_launch(void* const* d_in, const int* in_sizes, int n_in,
                              void* d_out, int out_size, void* d_ws, size_t ws_size,
                              hipStream_t stream) {
    const float* x  = (const float*)d_in[0];
    const float* Wq = (const float*)d_in[1];
    const float* bq = (const float*)d_in[2];
    const float* Wk = (const float*)d_in[3];
    const float* bk = (const float*)d_in[4];
    const float* Wv = (const float*)d_in[5];
    const float* bv = (const float*)d_in[6];
    const float* W1 = (const float*)d_in[7];
    const float* b1 = (const float*)d_in[8];
    const float* W2 = (const float*)d_in[9];
    const float* b2 = (const float*)d_in[10];
    float* out = (float*)d_out;

    char* ws = (char*)d_ws;
    size_t off = 0;
    auto alloc = [&](size_t bytes) { void* p = ws + off; off += (bytes + 255) & ~(size_t)255; return p; };
    u16* x16    = (u16*)alloc(8192ull * 512 * 2);       //  8.4 MB fp16
    u16* Wqk16  = (u16*)alloc(1024ull * 512 * 2);       //  Wq rows 0-511, Wk rows 512-1023
    u16* Wv16   = (u16*)alloc(512ull * 512 * 2);
    u16* W116   = (u16*)alloc(2048ull * 512 * 2);
    u16* W216   = (u16*)alloc(512ull * 2048 * 2);
    float* bqk  = (float*)alloc(1024 * 4);
    u16* pbuf   = (u16*)alloc(4ull * 2048 * 2048 * 2);  // 33.6 MB: qk lives here first, then P
    u16* vt     = (u16*)alloc(4ull * 512 * 2048 * 2);   //  8.4 MB fp16 [b][d][s]
    float* scores = (float*)alloc(4ull * 2048 * 2048 * 4); // 67.1 MB
    u16* qk   = pbuf;                   // fp16 [8192][1024]: q cols 0-511, k cols 512-1023
    u16* P    = pbuf;                   // fp16 [4][2048][2048]; qk dead after scores GEMM
    u16* attn = x16;                    // fp16 [8192][512]; x dead after projections
    u16* h    = (u16*)scores;           // fp16 [8192][2048]; scores dead after softmax
    if (ws_size < off) return;          // scratch too small: fail validation loudly

    dim3 blk(256), blk2(512);

    // one-time operand conversion (2 dispatches)
    cvt_f32_f16<<<dim3(4096), blk, 0, stream>>>(x, x16, 8192 * 512 / 4);
    cvt_weights<<<dim3(2817), blk, 0, stream>>>(Wq, Wk, Wv, W1, W2, bq, bk,
                                                Wqk16, Wv16, W116, W216, bqk);

    // qk = x @ [Wq;Wk]^T + [bq;bk]   (fp16 out)              1024 blocks
    gemm16<64, 1, false, 2, u16><<<dim3(16, 64, 1), blk, 0, stream>>>(
        x16, Wqk16, bqk, qk, 512, 512, 512, 1024, 0, 0, 0);
    // vt[b][d][s] = (x @ Wv^T + bv)^T                         512 blocks, splitK=2
    gemm16<64, 2, false, 3, u16><<<dim3(8, 64, 1), blk2, 0, stream>>>(
        x16, Wv16, bv, vt, 512, 512, 512, 0, 0, 0, 0);
    // scores[b] = q[b] @ k[b]^T   (fp32 out)                  1024 blocks
    gemm16<128, 1, false, 0, float><<<dim3(16, 16, 4), blk, 0, stream>>>(
        qk, qk + 512, nullptr, scores, 512, 1024, 1024, 2048,
        2048L * 1024, 2048L * 1024, 2048L * 2048);
    // P = softmax(scores) -> fp16 (overwrites dead qk region)
    softmax_rows<<<dim3(8192), blk, 0, stream>>>(scores, P);
    // attn[b] = P[b] @ V[b]   (fp16 out)                      512 blocks, splitK=2
    gemm16<64, 2, false, 2, u16><<<dim3(8, 16, 4), blk2, 0, stream>>>(
        P, vt, nullptr, attn, 2048, 2048, 2048, 512,
        2048L * 2048, 512L * 2048, 2048L * 512);
    // h = relu(attn @ W1^T + b1)   (fp16 out)                 1024 blocks
    gemm16<128, 1, true, 2, u16><<<dim3(16, 64, 1), blk, 0, stream>>>(
        attn, W116, b1, h, 512, 512, 512, 2048, 0, 0, 0);
    // out = h @ W2^T + b2   (fp32 out)                        512 blocks, splitK=2
    gemm16<64, 2, false, 0, float><<<dim3(8, 64, 1), blk2, 0, stream>>>(
        h, W216, b2, out, 2048, 2048, 2048, 512, 0, 0, 0);
}